// Round 1
// baseline (2613.114 us; speedup 1.0000x reference)
//
#include <hip/hip_runtime.h>
#include <cstdint>
#include <cstddef>

#define BN 256      // batch
#define HN 512      // hidden
#define TSN 128     // src len
#define TTN 32      // tgt len
#define NSL 16      // gate-dim slices
#define SRN 128     // gate rows per slice (4 gate types x 32 h-cols)

typedef __fp16 f16;
typedef __fp16 f16x8 __attribute__((ext_vector_type(8)));
typedef float  f32x4 __attribute__((ext_vector_type(4)));

// ---- workspace layout (bytes) ----
static constexpr size_t WQ_OFF  = 0;                        // 6 matrices, f16, slice-major [m][j][r][k]
static constexpr size_t WQ_MAT  = (size_t)NSL*SRN*HN*2;     // 2 MiB each
static constexpr size_t HS0_OFF = WQ_OFF + 6*WQ_MAT;        // enc L0 h for all t: slots 0..128 (slot0 = zeros)
static constexpr size_t HS_SLOT = (size_t)BN*HN*2;          // 256 KiB
static constexpr size_t H1_OFF  = HS0_OFF + 129*HS_SLOT;    // h1 double buffer (slot0 zeroed)
static constexpr size_t H0_OFF  = H1_OFF + 2*HS_SLOT;       // dec h0 double buffer
static constexpr size_t C0_OFF  = H0_OFF + 2*HS_SLOT;       // enc L0 final c (f32)
static constexpr size_t C1_OFF  = C0_OFF + (size_t)BN*HN*4; // enc L1 final c (f32)
static constexpr size_t YP_OFF  = C1_OFF + (size_t)BN*HN*4; // y partials [B][16] f32
static constexpr size_t BAR_OFF = YP_OFF + (size_t)BN*NSL*4;// barrier counters
// counters (each padded to 32 ints): P1: 0..15, P3: 16..31, P4: 32..39, full: 40

__device__ __forceinline__ float sigm(float x){ return 1.f/(1.f+__expf(-x)); }
__device__ __forceinline__ float tanh_(float x){
  float t = __expf(-2.f*fabsf(x));
  float r = (1.f-t)/(1.f+t);
  return x<0.f ? -r : r;
}

// group spin-barrier: release-add, relaxed spin, one acquire load (avoids L2-inv storm while polling)
__device__ __forceinline__ void gbar(int* c, int target){
  __syncthreads();
  if (threadIdx.x==0){
    __hip_atomic_fetch_add(c, 1, __ATOMIC_RELEASE, __HIP_MEMORY_SCOPE_AGENT);
    while (__hip_atomic_load(c, __ATOMIC_RELAXED, __HIP_MEMORY_SCOPE_AGENT) < target){
      __builtin_amdgcn_s_sleep(2);
    }
    (void)__hip_atomic_load(c, __ATOMIC_ACQUIRE, __HIP_MEMORY_SCOPE_AGENT);
  }
  __syncthreads();
}

// Load a weight slice as register-resident MFMA B-fragments.
// wave wv covers kt = wv*4 .. wv*4+3 (K = wv*128 .. wv*128+127), all 8 N-tiles.
// B-frag (16x16x32): lane l -> col = l&15, k = 8*(l>>4)+e.
__device__ __forceinline__ void load_bslice(const f16* wsl, int lane, int wv, f16x8 (&bw)[8][4]){
  const int rr = lane & 15;
  const int ko = ((lane>>4)<<3) + wv*128;
  #pragma unroll
  for (int nt=0; nt<8; ++nt){
    const f16* p = wsl + (size_t)(nt*16+rr)*HN + ko;
    #pragma unroll
    for (int kk=0; kk<4; ++kk) bw[nt][kk] = *(const f16x8*)(p + kk*32);
  }
}

// acc += A(h rows, f16, row stride HN) x B(slice). A-frag: lane l -> row = l&15 (+16*mt), k = 8*(l>>4)+e.
template<int MT>
__device__ __forceinline__ void gemm_acc(const f16* ab, int lane, int wv,
                                         const f16x8 (&bw)[8][4], f32x4 (&acc)[MT][8]){
  const int rr = lane & 15;
  const int ko = ((lane>>4)<<3) + wv*128;
  #pragma unroll
  for (int mt=0; mt<MT; ++mt){
    const f16* p = ab + (size_t)(mt*16+rr)*HN + ko;
    f16x8 a[4];
    #pragma unroll
    for (int kk=0; kk<4; ++kk) a[kk] = *(const f16x8*)(p + kk*32);
    #pragma unroll
    for (int kk=0; kk<4; ++kk){
      #pragma unroll
      for (int nt=0; nt<8; ++nt)
        acc[mt][nt] = __builtin_amdgcn_mfma_f32_16x16x32_f16(a[kk], bw[nt][kk], acc[mt][nt], 0, 0, 0);
    }
  }
}

// write per-wave f32 partials to LDS. C/D frag: col = l&15, row = (l>>4)*4 + i  (learn_hip m89)
template<int MT>
__device__ __forceinline__ void wpart(float (*gS)[32][132], const f32x4 (&acc)[MT][8], int lane, int wv){
  const int c0 = lane & 15, r0 = (lane>>4)*4;
  #pragma unroll
  for (int mt=0; mt<MT; ++mt)
    #pragma unroll
    for (int nt=0; nt<8; ++nt)
      #pragma unroll
      for (int i=0; i<4; ++i)
        gS[wv][mt*16+r0+i][nt*16+c0] = acc[mt][nt][i];
}

__device__ __forceinline__ float gsum(const float (*gS)[32][132], int row, int r){
  return gS[0][row][r] + gS[1][row][r] + gS[2][row][r] + gS[3][row][r];
}

// ---- prologue: zero the state that must be zero every call ----
__global__ void k_init(uint8_t* ws){
  const int i = blockIdx.x*256 + threadIdx.x;   // grid 256x256 = 65536
  float* a = (float*)(ws + HS0_OFF);            // hs0 slot 0 (h=0 at t=-1), 65536 f32 = 256KB
  float* b = (float*)(ws + H1_OFF);             // h1 slot 0
  int*   c = (int*)(ws + BAR_OFF);
  a[i] = 0.f;
  b[i] = 0.f;
  if (i < 2048) c[i] = 0;
}

// ---- prologue: f32 -> f16 slice-major weight scatter ----
__global__ void k_wconv(const float* s0, const float* s1, const float* s2,
                        const float* s3, const float* s4, const float* s5, f16* dst){
  const int i = blockIdx.x*256 + threadIdx.x;   // 0 .. 6*2^20
  const int k = i & 511, r = (i>>9)&127, j = (i>>16)&15, m = i>>20;
  const float* s = (m==0)?s0:(m==1)?s1:(m==2)?s2:(m==3)?s3:(m==4)?s4:s5;
  const int R = (r>>5)*512 + j*32 + (r&31);     // global gate row
  dst[i] = (f16)s[(size_t)R*HN + k];
}

__global__ void __launch_bounds__(256,1) k_main(
    const float* __restrict__ src,   const float* __restrict__ wih0e, const float* __restrict__ b0e,
    const float* __restrict__ b1e,   const float* __restrict__ wih0d, const float* __restrict__ b0d,
    const float* __restrict__ b1d,   const float* __restrict__ projw, const float* __restrict__ projb,
    uint8_t* __restrict__ ws, float* __restrict__ out)
{
  __shared__ float gS[4][32][132];          // per-wave K-partials
  __shared__ float srcS[16][TSN];
  __shared__ float wihS[SRN], bS[SRN], b2S[SRN], pwS[32], yS[32];

  const int wg = blockIdx.x, tid = threadIdx.x;
  const int lane = tid & 63, wv = tid >> 6;

  const f16* wq = (const f16*)(ws + WQ_OFF);
  f16* hs0 = (f16*)(ws + HS0_OFF);
  f16* h1b = (f16*)(ws + H1_OFF);
  f16* h0b = (f16*)(ws + H0_OFF);
  float* c0b = (float*)(ws + C0_OFF);
  float* c1b = (float*)(ws + C1_OFF);
  float* ypb = (float*)(ws + YP_OFF);
  int* bars = (int*)(ws + BAR_OFF);

  //================= Phase 1: encoder layer 0 (128 steps) =================
  {
    const int bg = wg & 15, j = wg >> 4;     // bg = blockIdx%16 -> whole group on one XCD (heuristic only)
    f16x8 bw[8][4];
    load_bslice(wq + (size_t)(0*NSL + j)*SRN*HN, lane, wv, bw);
    for (int i=tid; i<SRN; i+=256){
      int R = (i>>5)*512 + j*32 + (i&31);
      wihS[i] = wih0e[R]; bS[i] = b0e[R];
    }
    for (int i=tid; i<16*TSN; i+=256)
      srcS[i>>7][i&127] = src[(size_t)(bg*16 + (i>>7))*TSN + (i&127)];
    __syncthreads();

    float creg[2] = {0.f, 0.f};
    const int crow = tid >> 4, ckl = (tid & 15)*2;
    int* ctr = bars + bg*32;

    for (int t=0; t<TSN; ++t){
      f32x4 acc[1][8];
      #pragma unroll
      for (int nt=0; nt<8; ++nt) acc[0][nt] = f32x4{0.f,0.f,0.f,0.f};
      gemm_acc<1>(hs0 + (size_t)t*BN*HN + (size_t)bg*16*HN, lane, wv, bw, acc);
      wpart<1>(gS, acc, lane, wv);
      __syncthreads();

      const float xs = srcS[crow][t];
      float hv[2];
      #pragma unroll
      for (int q=0; q<2; ++q){
        const int kl = ckl + q;
        float gi = gsum(gS, crow, kl)      + xs*wihS[kl]      + bS[kl];
        float gf = gsum(gS, crow, 32+kl)   + xs*wihS[32+kl]   + bS[32+kl];
        float gg = gsum(gS, crow, 64+kl)   + xs*wihS[64+kl]   + bS[64+kl];
        float go = gsum(gS, crow, 96+kl)   + xs*wihS[96+kl]   + bS[96+kl];
        float cc = sigm(gf)*creg[q] + sigm(gi)*tanh_(gg);
        creg[q] = cc;
        hv[q] = sigm(go)*tanh_(cc);
      }
      union { f16 h2[2]; uint32_t u; } pk;
      pk.h2[0] = (f16)hv[0]; pk.h2[1] = (f16)hv[1];
      *(uint32_t*)(hs0 + (size_t)(t+1)*BN*HN + (size_t)(bg*16+crow)*HN + j*32 + ckl) = pk.u;

      gbar(ctr, (t+1)*16);
    }
    c0b[(size_t)(bg*16+crow)*HN + j*32 + ckl]     = creg[0];
    c0b[(size_t)(bg*16+crow)*HN + j*32 + ckl + 1] = creg[1];
  }
  gbar(bars + 40*32, 256);

  //================= Phase 3: encoder layer 1 (128 steps, gx fused) =================
  {
    const int bg = wg & 15, j = wg >> 4;
    f16x8 bwi[8][4], bwh[8][4];
    load_bslice(wq + (size_t)(1*NSL + j)*SRN*HN, lane, wv, bwi);   // enc W_ih1
    load_bslice(wq + (size_t)(2*NSL + j)*SRN*HN, lane, wv, bwh);   // enc W_hh1
    for (int i=tid; i<SRN; i+=256){
      int R = (i>>5)*512 + j*32 + (i&31);
      bS[i] = b1e[R];
    }
    __syncthreads();

    float creg[2] = {0.f, 0.f};
    const int crow = tid >> 4, ckl = (tid & 15)*2;
    int* ctr = bars + (16+bg)*32;

    for (int t=0; t<TSN; ++t){
      f32x4 acc[1][8];
      #pragma unroll
      for (int nt=0; nt<8; ++nt) acc[0][nt] = f32x4{0.f,0.f,0.f,0.f};
      gemm_acc<1>(hs0 + (size_t)(t+1)*BN*HN + (size_t)bg*16*HN, lane, wv, bwi, acc); // gx = x_t @ W_ih1^T
      gemm_acc<1>(h1b + (size_t)(t&1)*BN*HN + (size_t)bg*16*HN, lane, wv, bwh, acc); // + h1 @ W_hh1^T
      wpart<1>(gS, acc, lane, wv);
      __syncthreads();

      float hv[2];
      #pragma unroll
      for (int q=0; q<2; ++q){
        const int kl = ckl + q;
        float gi = gsum(gS, crow, kl)    + bS[kl];
        float gf = gsum(gS, crow, 32+kl) + bS[32+kl];
        float gg = gsum(gS, crow, 64+kl) + bS[64+kl];
        float go = gsum(gS, crow, 96+kl) + bS[96+kl];
        float cc = sigm(gf)*creg[q] + sigm(gi)*tanh_(gg);
        creg[q] = cc;
        hv[q] = sigm(go)*tanh_(cc);
      }
      union { f16 h2[2]; uint32_t u; } pk;
      pk.h2[0] = (f16)hv[0]; pk.h2[1] = (f16)hv[1];
      *(uint32_t*)(h1b + (size_t)((t+1)&1)*BN*HN + (size_t)(bg*16+crow)*HN + j*32 + ckl) = pk.u;

      gbar(ctr, (t+1)*16);
    }
    c1b[(size_t)(bg*16+crow)*HN + j*32 + ckl]     = creg[0];
    c1b[(size_t)(bg*16+crow)*HN + j*32 + ckl + 1] = creg[1];
  }
  gbar(bars + 40*32, 512);

  //================= Phase 4: decoder (32 steps, 2 roles) =================
  {
    const int bg = wg & 7, rest = wg >> 3;
    const int role = rest & 1, j = rest >> 1;   // role0: W_hh0+cell0 ; role1: W_ih1+W_hh1+cell1+proj
    f16x8 bwa[8][4], bwb[8][4];
    if (role == 0){
      load_bslice(wq + (size_t)(3*NSL + j)*SRN*HN, lane, wv, bwa); // dec W_hh0
    } else {
      load_bslice(wq + (size_t)(4*NSL + j)*SRN*HN, lane, wv, bwa); // dec W_ih1
      load_bslice(wq + (size_t)(5*NSL + j)*SRN*HN, lane, wv, bwb); // dec W_hh1
    }
    for (int i=tid; i<SRN; i+=256){
      int R = (i>>5)*512 + j*32 + (i&31);
      wihS[i] = wih0d[R]; bS[i] = b0d[R]; b2S[i] = b1d[R];
    }
    if (tid < 32) pwS[tid] = projw[j*32 + tid];
    const float pb = projb[0];

    const int crow = tid >> 3, ckl = (tid & 7)*4;
    float creg[4];
    {
      const float* csrc = (role==0) ? c0b : c1b;
      #pragma unroll
      for (int q=0; q<4; ++q)
        creg[q] = csrc[(size_t)(bg*32+crow)*HN + j*32 + ckl + q];
    }
    __syncthreads();

    int* ctr = bars + (32+bg)*32;
    int ep = 0;
    f32x4 accR[2][8];   // role1 acc persists across the mid-step barrier

    for (int t=0; t<TTN; ++t){
      //---- sub A ----
      if (role == 0){
        if (tid < 32){
          float y;
          if (t == 0) y = src[(size_t)(bg*32+tid)*TSN + (TSN-1)];
          else {
            y = pb;
            #pragma unroll
            for (int jj=0; jj<NSL; ++jj) y += ypb[(size_t)(bg*32+tid)*NSL + jj];
          }
          yS[tid] = y;
          if (j == 0 && t > 0) out[(size_t)(bg*32+tid)*TTN + (t-1)] = y;
        }
        __syncthreads();

        f32x4 acc[2][8];
        #pragma unroll
        for (int mt=0; mt<2; ++mt)
          #pragma unroll
          for (int nt=0; nt<8; ++nt) acc[mt][nt] = f32x4{0.f,0.f,0.f,0.f};
        const f16* hb = (t==0) ? (hs0 + (size_t)TSN*BN*HN + (size_t)bg*32*HN)
                               : (h0b + (size_t)(t&1)*BN*HN + (size_t)bg*32*HN);
        gemm_acc<2>(hb, lane, wv, bwa, acc);
        wpart<2>(gS, acc, lane, wv);
        __syncthreads();

        const float yv = yS[crow];
        float hv[4];
        #pragma unroll
        for (int q=0; q<4; ++q){
          const int kl = ckl + q;
          float gi = gsum(gS, crow, kl)    + yv*wihS[kl]    + bS[kl];
          float gf = gsum(gS, crow, 32+kl) + yv*wihS[32+kl] + bS[32+kl];
          float gg = gsum(gS, crow, 64+kl) + yv*wihS[64+kl] + bS[64+kl];
          float go = gsum(gS, crow, 96+kl) + yv*wihS[96+kl] + bS[96+kl];
          float cc = sigm(gf)*creg[q] + sigm(gi)*tanh_(gg);
          creg[q] = cc;
          hv[q] = sigm(go)*tanh_(cc);
        }
        union { f16 h4[4]; uint2 u2; } pk;
        #pragma unroll
        for (int q=0; q<4; ++q) pk.h4[q] = (f16)hv[q];
        *(uint2*)(h0b + (size_t)((t+1)&1)*BN*HN + (size_t)(bg*32+crow)*HN + j*32 + ckl) = pk.u2;
      } else {
        #pragma unroll
        for (int mt=0; mt<2; ++mt)
          #pragma unroll
          for (int nt=0; nt<8; ++nt) accR[mt][nt] = f32x4{0.f,0.f,0.f,0.f};
        gemm_acc<2>(h1b + (size_t)bg*32*HN, lane, wv, bwb, accR);  // W_hh1 @ h1_prev
      }
      gbar(ctr, (++ep)*32);

      //---- sub B ----
      if (role == 1){
        gemm_acc<2>(h0b + (size_t)((t+1)&1)*BN*HN + (size_t)bg*32*HN, lane, wv, bwa, accR); // + W_ih1 @ h0_new
        wpart<2>(gS, accR, lane, wv);
        __syncthreads();

        float hv[4];
        #pragma unroll
        for (int q=0; q<4; ++q){
          const int kl = ckl + q;
          float gi = gsum(gS, crow, kl)    + b2S[kl];
          float gf = gsum(gS, crow, 32+kl) + b2S[32+kl];
          float gg = gsum(gS, crow, 64+kl) + b2S[64+kl];
          float go = gsum(gS, crow, 96+kl) + b2S[96+kl];
          float cc = sigm(gf)*creg[q] + sigm(gi)*tanh_(gg);
          creg[q] = cc;
          hv[q] = sigm(go)*tanh_(cc);
        }
        union { f16 h4[4]; uint2 u2; } pk;
        #pragma unroll
        for (int q=0; q<4; ++q) pk.h4[q] = (f16)hv[q];
        *(uint2*)(h1b + (size_t)(bg*32+crow)*HN + j*32 + ckl) = pk.u2;

        float pp = hv[0]*pwS[ckl] + hv[1]*pwS[ckl+1] + hv[2]*pwS[ckl+2] + hv[3]*pwS[ckl+3];
        pp += __shfl_xor(pp, 1);
        pp += __shfl_xor(pp, 2);
        pp += __shfl_xor(pp, 4);
        if ((tid & 7) == 0) ypb[(size_t)(bg*32+crow)*NSL + j] = pp;
      }
      gbar(ctr, (++ep)*32);
    }

    // epilogue: y for t = 31
    if (role == 0 && j == 0 && tid < 32){
      float y = pb;
      #pragma unroll
      for (int jj=0; jj<NSL; ++jj) y += ypb[(size_t)(bg*32+tid)*NSL + jj];
      out[(size_t)(bg*32+tid)*TTN + 31] = y;
    }
  }
}

extern "C" void kernel_launch(void* const* d_in, const int* in_sizes, int n_in,
                              void* d_out, int out_size, void* d_ws, size_t ws_size,
                              hipStream_t stream)
{
  (void)in_sizes; (void)n_in; (void)out_size; (void)ws_size;
  const float* src   = (const float*)d_in[0];
  const float* wih0e = (const float*)d_in[1];
  const float* hh0e  = (const float*)d_in[2];
  const float* b0e   = (const float*)d_in[3];
  const float* ih1e  = (const float*)d_in[4];
  const float* hh1e  = (const float*)d_in[5];
  const float* b1e   = (const float*)d_in[6];
  const float* wih0d = (const float*)d_in[7];
  const float* hh0d  = (const float*)d_in[8];
  const float* b0d   = (const float*)d_in[9];
  const float* ih1d  = (const float*)d_in[10];
  const float* hh1d  = (const float*)d_in[11];
  const float* b1d   = (const float*)d_in[12];
  const float* projw = (const float*)d_in[13];
  const float* projb = (const float*)d_in[14];
  uint8_t* ws = (uint8_t*)d_ws;
  float* out = (float*)d_out;

  k_init<<<dim3(256), dim3(256), 0, stream>>>(ws);
  k_wconv<<<dim3(6*NSL*SRN*HN/256), dim3(256), 0, stream>>>(hh0e, ih1e, hh1e, hh0d, ih1d, hh1d,
                                                            (f16*)(ws + WQ_OFF));
  k_main<<<dim3(256), dim3(256), 0, stream>>>(src, wih0e, b0e, b1e, wih0d, b0d, b1d,
                                              projw, projb, ws, out);
}

// Round 2
// 1258.901 us; speedup vs baseline: 2.0757x; 2.0757x over previous
//
#include <hip/hip_runtime.h>
#include <cstdint>
#include <cstddef>

#define BN 256      // batch
#define HN 512      // hidden
#define TSN 128     // src len
#define TTN 32      // tgt len
#define NSL 16      // gate-dim slices
#define SRN 128     // gate rows per slice (4 gates x 32 h-cols)
#define NG  8       // batch groups of 32 rows

typedef __fp16 f16;
typedef __fp16 f16x8 __attribute__((ext_vector_type(8)));
typedef float  f32x4 __attribute__((ext_vector_type(4)));
typedef unsigned int u32;
typedef unsigned int u32x2 __attribute__((ext_vector_type(2)));

// ---- workspace layout (bytes) ----
static constexpr size_t WQ_OFF  = 0;                        // 6 matrices, f16, slice-major
static constexpr size_t WQ_MAT  = (size_t)NSL*SRN*HN*2;     // 2 MiB each
static constexpr size_t HS0_OFF = WQ_OFF + 6*WQ_MAT;        // enc L0 h history, slots 0..128
static constexpr size_t HS_SLOT = (size_t)BN*HN*2;          // 256 KiB
static constexpr size_t H1_OFF  = HS0_OFF + 129*HS_SLOT;    // h1 double buffer (slot0 zeroed)
static constexpr size_t H0_OFF  = H1_OFF + 2*HS_SLOT;       // dec h0 double buffer
static constexpr size_t YP_OFF  = H0_OFF + 2*HS_SLOT;       // y partials [B][16] f32
static constexpr size_t BAR_OFF = YP_OFF + (size_t)BN*NSL*4;// flag arrays (device-coherent)
// flags (ints): F0[8][16] @+0, F1[8][16] @+128, FD0[8][16] @+256, FD1[8][16] @+384

__device__ __forceinline__ float sigm(float x){ return 1.f/(1.f+__expf(-x)); }
__device__ __forceinline__ float tanh_(float x){
  float t = __expf(-2.f*fabsf(x));
  float r = (1.f-t)/(1.f+t);
  return x<0.f ? -r : r;
}

//========== device-coherent (sc0 sc1) asm memory ops ==========
__device__ __forceinline__ f16x8 ldg16_cv(const f16* p){
  f32x4 r;
  asm volatile("global_load_dwordx4 %0, %1, off sc0 sc1" : "=v"(r) : "v"(p));
  return __builtin_bit_cast(f16x8, r);
}
__device__ __forceinline__ void stg8_cv(f16* p, u32x2 v){
  asm volatile("global_store_dwordx2 %0, %1, off sc0 sc1" :: "v"(p), "v"(v) : "memory");
}
__device__ __forceinline__ void stg4i_cv(int* p, int v){
  asm volatile("global_store_dword %0, %1, off sc0 sc1" :: "v"(p), "v"(v) : "memory");
}
__device__ __forceinline__ void stg4f_cv(float* p, float v){
  asm volatile("global_store_dword %0, %1, off sc0 sc1" :: "v"(p), "v"(v) : "memory");
}
__device__ __forceinline__ void vmwait(){
  asm volatile("s_waitcnt vmcnt(0)" ::: "memory");
  __builtin_amdgcn_sched_barrier(0);
}
// wave0 polls 16 packed flags (one 64B line) until all >= target; WG-wide barrier after.
__device__ __forceinline__ void wait16(const int* f, int target){
  if (threadIdx.x < 64){
    const int* p = f + (threadIdx.x & 15);
    int v;
    for(;;){
      asm volatile("global_load_dword %0, %1, off sc0 sc1\n\ts_waitcnt vmcnt(0)"
                   : "=v"(v) : "v"(p) : "memory");
      if (__all(v >= target)) break;
    }
  }
  __syncthreads();
}
// publish: drain this wave's stores, WG barrier, then one flag store.
__device__ __forceinline__ void post(int* slot, int v){
  vmwait();
  __syncthreads();
  if (threadIdx.x == 0) stg4i_cv(slot, v);
}

//========== MFMA fragment helpers ==========
// B-frag slice: wave wv covers K = wv*128..+127, all 8 N-tiles. Plain cached loads.
__device__ __forceinline__ void load_bslice(const f16* wsl, int lane, int wv, f16x8 (&bw)[8][4]){
  const int rr = lane & 15;
  const int ko = ((lane>>4)<<3) + wv*128;
  #pragma unroll
  for (int nt=0; nt<8; ++nt){
    const f16* p = wsl + (size_t)(nt*16+rr)*HN + ko;
    #pragma unroll
    for (int kk=0; kk<4; ++kk) bw[nt][kk] = *(const f16x8*)(p + kk*32);
  }
}
// A-frags (recurrent h): device-coherent loads, no wait (caller does vmwait once).
template<int MT>
__device__ __forceinline__ void load_a_cv(const f16* ab, int lane, int wv, f16x8 (&A)[MT][4]){
  const int rr = lane & 15;
  const int ko = ((lane>>4)<<3) + wv*128;
  #pragma unroll
  for (int mt=0; mt<MT; ++mt){
    const f16* p = ab + (size_t)(mt*16+rr)*HN + ko;
    #pragma unroll
    for (int kk=0; kk<4; ++kk) A[mt][kk] = ldg16_cv(p + kk*32);
  }
}
template<int MT>
__device__ __forceinline__ void mfma_a(const f16x8 (&A)[MT][4], const f16x8 (&bw)[8][4],
                                       f32x4 (&acc)[MT][8]){
  #pragma unroll
  for (int mt=0; mt<MT; ++mt)
    #pragma unroll
    for (int kk=0; kk<4; ++kk)
      #pragma unroll
      for (int nt=0; nt<8; ++nt)
        acc[mt][nt] = __builtin_amdgcn_mfma_f32_16x16x32_f16(A[mt][kk], bw[nt][kk], acc[mt][nt], 0, 0, 0);
}
// C/D frag: col = l&15, row = (l>>4)*4 + i  (learn_hip m89)
template<int MT>
__device__ __forceinline__ void wpart(float (*gS)[32][132], const f32x4 (&acc)[MT][8], int lane, int wv){
  const int c0 = lane & 15, r0 = (lane>>4)*4;
  #pragma unroll
  for (int mt=0; mt<MT; ++mt)
    #pragma unroll
    for (int nt=0; nt<8; ++nt)
      #pragma unroll
      for (int i=0; i<4; ++i)
        gS[wv][mt*16+r0+i][nt*16+c0] = acc[mt][nt][i];
}
__device__ __forceinline__ float gsum(const float (*gS)[32][132], int row, int r){
  return gS[0][row][r] + gS[1][row][r] + gS[2][row][r] + gS[3][row][r];
}

//========== prologue kernels ==========
__global__ void k_init(uint8_t* ws){
  const int i = blockIdx.x*256 + threadIdx.x;   // 65536 threads
  float* a = (float*)(ws + HS0_OFF);            // hs0 slot0 = zeros (256KB)
  float* b = (float*)(ws + H1_OFF);             // h1 slot0 = zeros
  int*   c = (int*)(ws + BAR_OFF);
  a[i] = 0.f;
  b[i] = 0.f;
  if (i < 2048) c[i] = 0;
}
__global__ void k_wconv(const float* s0, const float* s1, const float* s2,
                        const float* s3, const float* s4, const float* s5, f16* dst){
  const int i = blockIdx.x*256 + threadIdx.x;
  const int k = i & 511, r = (i>>9)&127, j = (i>>16)&15, m = i>>20;
  const float* s = (m==0)?s0:(m==1)?s1:(m==2)?s2:(m==3)?s3:(m==4)?s4:s5;
  const int R = (r>>5)*512 + j*32 + (r&31);
  dst[i] = (f16)s[(size_t)R*HN + k];
}

//========== main persistent kernel ==========
__global__ void __launch_bounds__(256,1) k_main(
    const float* __restrict__ src,   const float* __restrict__ wih0e, const float* __restrict__ b0e,
    const float* __restrict__ b1e,   const float* __restrict__ wih0d, const float* __restrict__ b0d,
    const float* __restrict__ b1d,   const float* __restrict__ projw, const float* __restrict__ projb,
    uint8_t* __restrict__ ws, float* __restrict__ out)
{
  __shared__ float gS[4][32][132];
  __shared__ float srcS[32][TSN];
  __shared__ float wihS[SRN], bS[SRN], pwS[32], yS[32];

  const int wg = blockIdx.x, tid = threadIdx.x;
  const int lane = tid & 63, wv = tid >> 6;
  const int g = (wg >> 4) & 7, j = wg & 15;
  const bool teamA = (wg < 128);                 // teamA: enc L0 then dec cell0 ; teamB: enc L1 then dec cell1

  const f16* wq = (const f16*)(ws + WQ_OFF);
  f16* hs0 = (f16*)(ws + HS0_OFF);
  f16* h1b = (f16*)(ws + H1_OFF);
  f16* h0b = (f16*)(ws + H0_OFF);
  float* ypb = (float*)(ws + YP_OFF);
  int* F0  = (int*)(ws + BAR_OFF);
  int* F1  = F0 + 128;
  int* FD0 = F0 + 256;
  int* FD1 = F0 + 384;
  int* F0g = F0 + g*16, *F1g = F1 + g*16, *FD0g = FD0 + g*16, *FD1g = FD1 + g*16;

  const int crow = tid >> 3, ckl = (tid & 7)*4;  // cell mapping: 32 rows x (4 cols/thread)
  float creg[4] = {0.f,0.f,0.f,0.f};

  if (teamA){
    //================= encoder layer 0 =================
    f16x8 bw[8][4];
    load_bslice(wq + (size_t)(0*NSL + j)*SRN*HN, lane, wv, bw);
    for (int i=tid; i<SRN; i+=256){
      int R = (i>>5)*512 + j*32 + (i&31);
      wihS[i] = wih0e[R]; bS[i] = b0e[R];
    }
    for (int i=tid; i<32*TSN; i+=256)
      srcS[i>>7][i&127] = src[(size_t)(g*32 + (i>>7))*TSN + (i&127)];
    __syncthreads();

    for (int t=0; t<TSN; ++t){
      wait16(F0g, t);
      f16x8 A[2][4];
      load_a_cv<2>(hs0 + (size_t)t*BN*HN + (size_t)g*32*HN, lane, wv, A);
      vmwait();
      f32x4 acc[2][8];
      #pragma unroll
      for (int mt=0; mt<2; ++mt)
        #pragma unroll
        for (int nt=0; nt<8; ++nt) acc[mt][nt] = f32x4{0.f,0.f,0.f,0.f};
      mfma_a<2>(A, bw, acc);
      wpart<2>(gS, acc, lane, wv);
      __syncthreads();

      const float xs = srcS[crow][t];
      f16 hv[4];
      #pragma unroll
      for (int q=0; q<4; ++q){
        const int kl = ckl + q;
        float gi = gsum(gS, crow, kl)    + xs*wihS[kl]    + bS[kl];
        float gf = gsum(gS, crow, 32+kl) + xs*wihS[32+kl] + bS[32+kl];
        float gg = gsum(gS, crow, 64+kl) + xs*wihS[64+kl] + bS[64+kl];
        float go = gsum(gS, crow, 96+kl) + xs*wihS[96+kl] + bS[96+kl];
        float cc = sigm(gf)*creg[q] + sigm(gi)*tanh_(gg);
        creg[q] = cc;
        hv[q] = (f16)(sigm(go)*tanh_(cc));
      }
      union { f16 h4[4]; u32x2 u; } pk;
      #pragma unroll
      for (int q=0; q<4; ++q) pk.h4[q] = hv[q];
      stg8_cv(hs0 + (size_t)(t+1)*BN*HN + (size_t)(g*32+crow)*HN + j*32 + ckl, pk.u);
      post(F0g + j, t+1);
    }

    //================= decoder cell0 =================
    load_bslice(wq + (size_t)(3*NSL + j)*SRN*HN, lane, wv, bw);   // dec W_hh0
    for (int i=tid; i<SRN; i+=256){
      int R = (i>>5)*512 + j*32 + (i&31);
      wihS[i] = wih0d[R]; bS[i] = b0d[R];
    }
    const float pb = projb[0];
    __syncthreads();   // creg already holds c0 (same thread mapping)

    for (int t=0; t<TTN; ++t){
      // GEMM first (y-independent)
      if (t == 0) wait16(F0g, TSN); else wait16(FD0g, t);
      f16x8 A[2][4];
      const f16* hb = (t==0) ? (hs0 + (size_t)TSN*BN*HN + (size_t)g*32*HN)
                             : (h0b + (size_t)(t&1)*HS_SLOT/2 + (size_t)g*32*HN);
      load_a_cv<2>(hb, lane, wv, A);
      vmwait();
      f32x4 acc[2][8];
      #pragma unroll
      for (int mt=0; mt<2; ++mt)
        #pragma unroll
        for (int nt=0; nt<8; ++nt) acc[mt][nt] = f32x4{0.f,0.f,0.f,0.f};
      mfma_a<2>(A, bw, acc);
      wpart<2>(gS, acc, lane, wv);
      __syncthreads();

      // y feedback
      if (t == 0){
        if (tid < 32) yS[tid] = src[(size_t)(g*32+tid)*TSN + (TSN-1)];
      } else {
        wait16(FD1g, t);
        if (tid < 32){
          const float* pr = ypb + (size_t)(g*32+tid)*NSL;
          f32x4 r0,r1,r2,r3;
          asm volatile("global_load_dwordx4 %0, %4, off sc0 sc1\n\t"
                       "global_load_dwordx4 %1, %5, off sc0 sc1\n\t"
                       "global_load_dwordx4 %2, %6, off sc0 sc1\n\t"
                       "global_load_dwordx4 %3, %7, off sc0 sc1\n\t"
                       "s_waitcnt vmcnt(0)"
                       : "=&v"(r0),"=&v"(r1),"=&v"(r2),"=&v"(r3)
                       : "v"(pr),"v"(pr+4),"v"(pr+8),"v"(pr+12) : "memory");
          float y = pb + r0[0]+r0[1]+r0[2]+r0[3] + r1[0]+r1[1]+r1[2]+r1[3]
                       + r2[0]+r2[1]+r2[2]+r2[3] + r3[0]+r3[1]+r3[2]+r3[3];
          yS[tid] = y;
          if (j == 0) out[(size_t)(g*32+tid)*TTN + (t-1)] = y;
        }
      }
      __syncthreads();

      const float yv = yS[crow];
      f16 hv[4];
      #pragma unroll
      for (int q=0; q<4; ++q){
        const int kl = ckl + q;
        float gi = gsum(gS, crow, kl)    + yv*wihS[kl]    + bS[kl];
        float gf = gsum(gS, crow, 32+kl) + yv*wihS[32+kl] + bS[32+kl];
        float gg = gsum(gS, crow, 64+kl) + yv*wihS[64+kl] + bS[64+kl];
        float go = gsum(gS, crow, 96+kl) + yv*wihS[96+kl] + bS[96+kl];
        float cc = sigm(gf)*creg[q] + sigm(gi)*tanh_(gg);
        creg[q] = cc;
        hv[q] = (f16)(sigm(go)*tanh_(cc));
      }
      union { f16 h4[4]; u32x2 u; } pk;
      #pragma unroll
      for (int q=0; q<4; ++q) pk.h4[q] = hv[q];
      stg8_cv(h0b + (size_t)((t+1)&1)*HS_SLOT/2 + (size_t)(g*32+crow)*HN + j*32 + ckl, pk.u);
      post(FD0g + j, t+1);
    }

    // epilogue: y for t = 31
    if (j == 0){
      wait16(FD1g, TTN);
      if (tid < 32){
        const float* pr = ypb + (size_t)(g*32+tid)*NSL;
        f32x4 r0,r1,r2,r3;
        asm volatile("global_load_dwordx4 %0, %4, off sc0 sc1\n\t"
                     "global_load_dwordx4 %1, %5, off sc0 sc1\n\t"
                     "global_load_dwordx4 %2, %6, off sc0 sc1\n\t"
                     "global_load_dwordx4 %3, %7, off sc0 sc1\n\t"
                     "s_waitcnt vmcnt(0)"
                     : "=&v"(r0),"=&v"(r1),"=&v"(r2),"=&v"(r3)
                     : "v"(pr),"v"(pr+4),"v"(pr+8),"v"(pr+12) : "memory");
        float y = projb[0] + r0[0]+r0[1]+r0[2]+r0[3] + r1[0]+r1[1]+r1[2]+r1[3]
                           + r2[0]+r2[1]+r2[2]+r2[3] + r3[0]+r3[1]+r3[2]+r3[3];
        out[(size_t)(g*32+tid)*TTN + (TTN-1)] = y;
      }
    }
  } else {
    //================= encoder layer 1 =================
    f16x8 bwi[8][4], bwh[8][4];
    load_bslice(wq + (size_t)(1*NSL + j)*SRN*HN, lane, wv, bwi);   // enc W_ih1
    load_bslice(wq + (size_t)(2*NSL + j)*SRN*HN, lane, wv, bwh);   // enc W_hh1
    for (int i=tid; i<SRN; i+=256){
      int R = (i>>5)*512 + j*32 + (i&31);
      bS[i] = b1e[R];
    }
    __syncthreads();

    for (int t=0; t<TSN; ++t){
      wait16(F1g, t);
      f16x8 A[2][4];
      load_a_cv<2>(h1b + (size_t)(t&1)*HS_SLOT/2 + (size_t)g*32*HN, lane, wv, A);
      vmwait();
      f32x4 acc[2][8];
      #pragma unroll
      for (int mt=0; mt<2; ++mt)
        #pragma unroll
        for (int nt=0; nt<8; ++nt) acc[mt][nt] = f32x4{0.f,0.f,0.f,0.f};
      mfma_a<2>(A, bwh, acc);
      wait16(F0g, t+1);
      f16x8 A2[2][4];
      load_a_cv<2>(hs0 + (size_t)(t+1)*BN*HN + (size_t)g*32*HN, lane, wv, A2);
      vmwait();
      mfma_a<2>(A2, bwi, acc);
      wpart<2>(gS, acc, lane, wv);
      __syncthreads();

      f16 hv[4];
      #pragma unroll
      for (int q=0; q<4; ++q){
        const int kl = ckl + q;
        float gi = gsum(gS, crow, kl)    + bS[kl];
        float gf = gsum(gS, crow, 32+kl) + bS[32+kl];
        float gg = gsum(gS, crow, 64+kl) + bS[64+kl];
        float go = gsum(gS, crow, 96+kl) + bS[96+kl];
        float cc = sigm(gf)*creg[q] + sigm(gi)*tanh_(gg);
        creg[q] = cc;
        hv[q] = (f16)(sigm(go)*tanh_(cc));
      }
      union { f16 h4[4]; u32x2 u; } pk;
      #pragma unroll
      for (int q=0; q<4; ++q) pk.h4[q] = hv[q];
      stg8_cv(h1b + (size_t)((t+1)&1)*HS_SLOT/2 + (size_t)(g*32+crow)*HN + j*32 + ckl, pk.u);
      post(F1g + j, t+1);
    }

    //================= decoder cell1 + proj =================
    f16x8 (&bwa)[8][4] = bwi;  // dec W_ih1
    f16x8 (&bwb)[8][4] = bwh;  // dec W_hh1
    load_bslice(wq + (size_t)(4*NSL + j)*SRN*HN, lane, wv, bwa);
    load_bslice(wq + (size_t)(5*NSL + j)*SRN*HN, lane, wv, bwb);
    for (int i=tid; i<SRN; i+=256){
      int R = (i>>5)*512 + j*32 + (i&31);
      bS[i] = b1d[R];
    }
    if (tid < 32) pwS[tid] = projw[j*32 + tid];
    __syncthreads();   // creg already holds c1

    for (int t=0; t<TTN; ++t){
      if (t == 0) wait16(F1g, TSN); else wait16(FD1g, t);
      f16x8 A[2][4];
      load_a_cv<2>(h1b + (size_t)(t&1)*HS_SLOT/2 + (size_t)g*32*HN, lane, wv, A);
      vmwait();
      f32x4 acc[2][8];
      #pragma unroll
      for (int mt=0; mt<2; ++mt)
        #pragma unroll
        for (int nt=0; nt<8; ++nt) acc[mt][nt] = f32x4{0.f,0.f,0.f,0.f};
      mfma_a<2>(A, bwb, acc);                    // W_hh1 @ h1_t
      wait16(FD0g, t+1);
      f16x8 A2[2][4];
      load_a_cv<2>(h0b + (size_t)((t+1)&1)*HS_SLOT/2 + (size_t)g*32*HN, lane, wv, A2);
      vmwait();
      mfma_a<2>(A2, bwa, acc);                   // + W_ih1 @ h0_{t+1}
      wpart<2>(gS, acc, lane, wv);
      __syncthreads();

      f16 hv[4];
      float hvf[4];
      #pragma unroll
      for (int q=0; q<4; ++q){
        const int kl = ckl + q;
        float gi = gsum(gS, crow, kl)    + bS[kl];
        float gf = gsum(gS, crow, 32+kl) + bS[32+kl];
        float gg = gsum(gS, crow, 64+kl) + bS[64+kl];
        float go = gsum(gS, crow, 96+kl) + bS[96+kl];
        float cc = sigm(gf)*creg[q] + sigm(gi)*tanh_(gg);
        creg[q] = cc;
        hvf[q] = sigm(go)*tanh_(cc);
        hv[q] = (f16)hvf[q];
      }
      union { f16 h4[4]; u32x2 u; } pk;
      #pragma unroll
      for (int q=0; q<4; ++q) pk.h4[q] = hv[q];
      stg8_cv(h1b + (size_t)((t+1)&1)*HS_SLOT/2 + (size_t)(g*32+crow)*HN + j*32 + ckl, pk.u);

      float pp = hvf[0]*pwS[ckl] + hvf[1]*pwS[ckl+1] + hvf[2]*pwS[ckl+2] + hvf[3]*pwS[ckl+3];
      pp += __shfl_xor(pp, 1);
      pp += __shfl_xor(pp, 2);
      pp += __shfl_xor(pp, 4);
      if ((tid & 7) == 0) stg4f_cv(ypb + (size_t)(g*32+crow)*NSL + j, pp);
      post(FD1g + j, t+1);
    }
  }
}

extern "C" void kernel_launch(void* const* d_in, const int* in_sizes, int n_in,
                              void* d_out, int out_size, void* d_ws, size_t ws_size,
                              hipStream_t stream)
{
  (void)in_sizes; (void)n_in; (void)out_size; (void)ws_size;
  const float* src   = (const float*)d_in[0];
  const float* wih0e = (const float*)d_in[1];
  const float* hh0e  = (const float*)d_in[2];
  const float* b0e   = (const float*)d_in[3];
  const float* ih1e  = (const float*)d_in[4];
  const float* hh1e  = (const float*)d_in[5];
  const float* b1e   = (const float*)d_in[6];
  const float* wih0d = (const float*)d_in[7];
  const float* hh0d  = (const float*)d_in[8];
  const float* b0d   = (const float*)d_in[9];
  const float* ih1d  = (const float*)d_in[10];
  const float* hh1d  = (const float*)d_in[11];
  const float* b1d   = (const float*)d_in[12];
  const float* projw = (const float*)d_in[13];
  const float* projb = (const float*)d_in[14];
  uint8_t* ws = (uint8_t*)d_ws;
  float* out = (float*)d_out;

  k_init<<<dim3(256), dim3(256), 0, stream>>>(ws);
  k_wconv<<<dim3(6*NSL*SRN*HN/256), dim3(256), 0, stream>>>(hh0e, ih1e, hh1e, hh0d, ih1d, hh1d,
                                                            (f16*)(ws + WQ_OFF));
  k_main<<<dim3(256), dim3(256), 0, stream>>>(src, wih0e, b0e, b1e, wih0d, b0d, b1d,
                                              projw, projb, ws, out);
}